// Round 10
// baseline (331.724 us; speedup 1.0000x reference)
//
#include <hip/hip_runtime.h>
#include <stdint.h>
#include <stddef.h>

// ---------------- problem constants ----------------
#define SEQ   2048
#define BATCH 2
#define HID   2048
#define NH    16
#define HD    128
#define MTOT  (SEQ*BATCH)   // 4096
#define NQKV  (3*HID)       // 6144
#define KDIM  HID           // 2048
#define LOG2E 1.4426950408889634f

#define BK64    64
#define NT64    (KDIM/BK64)   // 32

typedef short  bf16x8 __attribute__((ext_vector_type(8)));  // 8 bf16 in 4 VGPRs
typedef float  f32x4  __attribute__((ext_vector_type(4)));

__device__ __forceinline__ unsigned short f2bf(float f) {
  union { float f; uint32_t u; } a; a.f = f;
  uint32_t r = a.u + 0x7fffu + ((a.u >> 16) & 1u);   // RNE
  return (unsigned short)(r >> 16);
}

__device__ __forceinline__ f32x4 mfma16(bf16x8 a, bf16x8 b, f32x4 c) {
  return __builtin_amdgcn_mfma_f32_16x16x32_bf16(a, b, c, 0, 0, 0);
}

// async global->LDS, 16B per lane; LDS dest = wave-uniform base + lane*16
__device__ __forceinline__ void gl_lds16(const unsigned short* g, unsigned short* l) {
  __builtin_amdgcn_global_load_lds(
      (const __attribute__((address_space(1))) void*)g,
      (__attribute__((address_space(3))) void*)l, 16, 0, 0);
}

// ---------------- fused fp32 -> bf16 convert (3 tensors, 1 launch) ----------------
__global__ void cvt3_f32_bf16(const float* __restrict__ a, unsigned short* __restrict__ oa, int na,
                              const float* __restrict__ b, unsigned short* __restrict__ ob, int nb,
                              const float* __restrict__ c, unsigned short* __restrict__ oc, int nc) {
  int i = blockIdx.x * blockDim.x + threadIdx.x;
  int stride = gridDim.x * blockDim.x;
  int ntot = na + nb + nc;
  for (; i < ntot; i += stride) {
    const float* src; unsigned short* dst; int j;
    if (i < na)           { src = a; dst = oa; j = i; }
    else if (i < na + nb) { src = b; dst = ob; j = i - na; }
    else                  { src = c; dst = oc; j = i - na - nb; }
    float4 f = reinterpret_cast<const float4*>(src)[j];
    ushort4 o;
    o.x = f2bf(f.x); o.y = f2bf(f.y); o.z = f2bf(f.z); o.w = f2bf(f.w);
    reinterpret_cast<ushort4*>(dst)[j] = o;
  }
}

// ---------------- V transpose: [bh][s][d] -> [bh][d][s] ----------------
__global__ __launch_bounds__(256) void transpose_v(
    const unsigned short* __restrict__ V, unsigned short* __restrict__ Vt) {
  __shared__ unsigned short tile[64][72];
  const int t  = threadIdx.x;
  const int bh = blockIdx.z;
  const int s0 = blockIdx.x * 64;
  const int d0 = blockIdx.y * 64;
  const size_t vb = (size_t)bh * SEQ * HD;
  const size_t tb = (size_t)bh * HD * SEQ;
#pragma unroll
  for (int p = 0; p < 2; ++p) {
    int r = p * 32 + (t >> 3);
    *(uint4*)&tile[r][(t & 7) * 8] =
        *(const uint4*)&V[vb + (size_t)(s0 + r) * HD + d0 + (t & 7) * 8];
  }
  __syncthreads();
#pragma unroll
  for (int p = 0; p < 2; ++p) {
    int dr = p * 32 + (t >> 3);
    int sc = (t & 7) * 8;
    unsigned short tmp[8];
#pragma unroll
    for (int e = 0; e < 8; ++e) tmp[e] = tile[sc + e][dr];
    *(uint4*)&Vt[tb + (size_t)(d0 + dr) * SEQ + s0 + sc] = *(const uint4*)tmp;
  }
}

// =====================================================================
// 8-phase 256x192 GEMM (qkv) — round-6 version (measured 120 us, 857 TF
// = the m97-structure ceiling).  BK=64, 512 thr = 8 waves (2M x 4N),
// per-wave 128x48 (acc[8][3]).  Grid 16x32 = 512 = 2 full dispatch waves.
// LDS: 2 x 56KB; involution granule swizzle LDS[r][g] = glob[r][g^(r&7)].
// Staging of tile t+1: ph0 B0,B64 | ph1 B128,A0 | ph2 A128,A64 | ph3 A192.
// vmcnt(4)@ph1, vmcnt(2)@ph3 — never 0 in steady state.
// =====================================================================

#define QBUFS 28672   // shorts per LDS buffer: A 16384 + B 12288

#define QSTA(R) gl_lds16(Asrc + (size_t)(R) * KDIM + koff, &db[((R) + w * 8) * 64])
#define QSTB(R) gl_lds16(Bsrc + (size_t)(R) * KDIM + koff, &db[16384 + ((R) + w * 8) * 64])

#define G8_SB()  asm volatile("s_barrier" ::: "memory")
#define G8_LGKM() do { asm volatile("s_waitcnt lgkmcnt(0)" ::: "memory");     \
                       __builtin_amdgcn_sched_barrier(0); } while (0)

#define G8_RDA(G) do {                                                        \
    p0 = *(const bf16x8*)&sb[abase + (2*(G)    ) * 1024 + ga0];               \
    p1 = *(const bf16x8*)&sb[abase + (2*(G)    ) * 1024 + ga1];               \
    p2 = *(const bf16x8*)&sb[abase + (2*(G) + 1) * 1024 + ga0];               \
    p3 = *(const bf16x8*)&sb[abase + (2*(G) + 1) * 1024 + ga1];               \
  } while (0)

#define G8_MFMA(G) do {                                                       \
    __builtin_amdgcn_s_setprio(1);                                            \
    _Pragma("unroll")                                                         \
    for (int n_ = 0; n_ < 3; ++n_) {                                          \
      acc[2*(G)][n_]     = mfma16(p0, bq0[n_], acc[2*(G)][n_]);               \
      acc[2*(G)][n_]     = mfma16(p1, bq1[n_], acc[2*(G)][n_]);               \
      acc[2*(G) + 1][n_] = mfma16(p2, bq0[n_], acc[2*(G) + 1][n_]);           \
      acc[2*(G) + 1][n_] = mfma16(p3, bq1[n_], acc[2*(G) + 1][n_]);           \
    }                                                                         \
    __builtin_amdgcn_sched_barrier(0);                                        \
    __builtin_amdgcn_s_setprio(0);                                            \
  } while (0)

#define G8_TILE(DOSTAGE, VM1, VM3) do {                                       \
    bf16x8 bq0[3], bq1[3], p0, p1, p2, p3;                                    \
    /* ---- phase 0 ---- */                                                   \
    _Pragma("unroll")                                                         \
    for (int n_ = 0; n_ < 3; ++n_) {                                          \
      bq0[n_] = *(const bf16x8*)&sb[bbase + n_ * 1024 + ga0];                 \
      bq1[n_] = *(const bf16x8*)&sb[bbase + n_ * 1024 + ga1];                 \
    }                                                                         \
    G8_RDA(0);                                                                \
    if (DOSTAGE) { QSTB(0); QSTB(64); }                                       \
    G8_SB(); G8_LGKM();                                                       \
    G8_MFMA(0);                                                               \
    G8_SB();                                                                  \
    /* ---- phase 1 ---- */                                                   \
    G8_RDA(1);                                                                \
    if (DOSTAGE) { QSTB(128); QSTA(0); }                                      \
    asm volatile("s_waitcnt " VM1 ::: "memory");                              \
    G8_SB(); G8_LGKM();                                                       \
    G8_MFMA(1);                                                               \
    G8_SB();                                                                  \
    /* ---- phase 2 ---- */                                                   \
    G8_RDA(2);                                                                \
    if (DOSTAGE) { QSTA(128); QSTA(64); }                                     \
    G8_SB(); G8_LGKM();                                                       \
    G8_MFMA(2);                                                               \
    G8_SB();                                                                  \
    /* ---- phase 3 ---- */                                                   \
    G8_RDA(3);                                                                \
    if (DOSTAGE) { QSTA(192); }                                               \
    asm volatile("s_waitcnt " VM3 ::: "memory");                              \
    G8_SB(); G8_LGKM();                                                       \
    G8_MFMA(3);                                                               \
    G8_SB();                                                                  \
  } while (0)

// grid: 512 blocks (16 m x 32 n), XCD-swizzled (512 % 8 == 0).
__global__ __launch_bounds__(512, 2) void qkv_gemm(
    const unsigned short* __restrict__ A,
    const unsigned short* __restrict__ B,
    const float* __restrict__ bias,
    unsigned short* __restrict__ Qo,
    unsigned short* __restrict__ Ko,
    unsigned short* __restrict__ Vo)
{
  __shared__ unsigned short smb[2 * QBUFS];   // 112 KB
  const int id  = blockIdx.x;
  const int swz = (id & 7) * 64 + (id >> 3);
  const int m0 = (swz >> 5) * 256, n0 = (swz & 31) * 192;
  const int t = threadIdx.x, l = t & 63, w = t >> 6;
  const int wm = w >> 2, wn = w & 3;
  const int fr = l & 15, fg = l >> 4;
  const int abase = (wm * 128 + fr) * 64;
  const int bbase = 16384 + (wn * 48 + fr) * 64;
  const int ga0 = ((fg     ) ^ (fr & 7)) * 8;
  const int ga1 = ((fg + 4 ) ^ (fr & 7)) * 8;
  const int srcrow = w * 8 + (l >> 3);
  const int sgr    = ((l & 7) ^ (l >> 3)) * 8;
  const unsigned short* Asrc = A + (size_t)(m0 + srcrow) * KDIM + sgr;
  const unsigned short* Bsrc = B + (size_t)(n0 + srcrow) * KDIM + sgr;
  f32x4 acc[8][3] = {};

  { // prologue: stage tile 0 (order: B0,B64,B128,A0,A128,A64,A192)
    unsigned short* db = smb;
    size_t koff = 0;
    QSTB(0); QSTB(64); QSTB(128);
    QSTA(0); QSTA(128); QSTA(64); QSTA(192);
  }
  asm volatile("s_waitcnt vmcnt(2)" ::: "memory");   // A64,A192 still in flight
  asm volatile("s_barrier" ::: "memory");

#pragma unroll 1
  for (int kt = 0; kt < NT64 - 1; ++kt) {
    const unsigned short* sb = &smb[(kt & 1) * QBUFS];
    unsigned short* db = &smb[((kt + 1) & 1) * QBUFS];
    size_t koff = (size_t)(kt + 1) * BK64;
    G8_TILE(1, "vmcnt(4)", "vmcnt(2)");
  }
  { // last tile: no staging; drain remaining A64,A192 at ph1
    const unsigned short* sb = &smb[((NT64 - 1) & 1) * QBUFS];
    unsigned short* db = smb;    // unused (DOSTAGE=0)
    size_t koff = 0; (void)koff;
    G8_TILE(0, "vmcnt(0)", "vmcnt(0)");
  }

  // epilogue: bias (+ q-scale fold) + scatter to [b][h][s][d] bf16
#pragma unroll
  for (int n = 0; n < 3; ++n) {
    int ncol = n0 + wn * 48 + n * 16 + fr;
    float bv = bias[ncol];
    int head = ncol / 384;
    int rem  = ncol - head * 384;
    int wi   = rem >> 7;          // 0=q 1=k 2=v
    int d    = rem & 127;
    unsigned short* dst = (wi == 0) ? Qo : ((wi == 1) ? Ko : Vo);
#pragma unroll
    for (int m = 0; m < 8; ++m) {
#pragma unroll
      for (int j = 0; j < 4; ++j) {
        int r = m0 + wm * 128 + m * 16 + fg * 4 + j;
        int s = r >> 1, bb = r & 1;
        float val = acc[m][n][j] + bv;
        if (wi == 0) val *= 0.08838834764831845f;   // fold 1/sqrt(128) into Q
        dst[(((size_t)(bb * NH + head)) * SEQ + s) * HD + d] = f2bf(val);
      }
    }
  }
}

// =====================================================================
// dense GEMM: round-4/6 structure (BM=256, BN=128, BK=64, 3-buf rotation)
// =====================================================================

#define GEMM_PRE()                                                            \
  const int t = threadIdx.x, l = t & 63, w = t >> 6;                          \
  const int wm = w >> 1, wn = w & 1;                                          \
  const int fr = l & 15, fg = l >> 4;                                         \
  const int fx = fr & 7;                                                      \
  const int srow = l >> 3;                                                    \
  const int sgr  = ((l & 7) ^ srow) * 8;                                      \
  const unsigned short* Aw = A + (size_t)(m0 + w * 32 + srow) * KDIM + sgr;   \
  const unsigned short* Bw = B + (size_t)(n0 + w * 16 + srow) * KDIM + sgr;   \
  unsigned short* smb = &sm[0][0];                                            \
  const int a0 = (wm * 64 + fr) * 64 + ((fg ^ fx) * 8);                       \
  const int a1 = (wm * 64 + fr) * 64 + (((4 + fg) ^ fx) * 8);                 \
  const int b0 = 16384 + (wn * 64 + fr) * 64 + ((fg ^ fx) * 8);               \
  const int b1 = 16384 + (wn * 64 + fr) * 64 + (((4 + fg) ^ fx) * 8);         \
  f32x4 acc[4][4] = {};

#define STAGE_AB(KT) do {                                                     \
    unsigned short* dst = &smb[((KT) % 3) * 24576];                           \
    const unsigned short* ap = Aw + (size_t)(KT) * BK64;                      \
    gl_lds16(ap,                    &dst[(w * 4 + 0) * 512]);                 \
    gl_lds16(ap + 8  * KDIM,        &dst[(w * 4 + 1) * 512]);                 \
    gl_lds16(ap + 16 * KDIM,        &dst[(w * 4 + 2) * 512]);                 \
    gl_lds16(ap + 24 * KDIM,        &dst[(w * 4 + 3) * 512]);                 \
    const unsigned short* bp = Bw + (size_t)(KT) * BK64;                      \
    gl_lds16(bp,                    &dst[16384 + (w * 2 + 0) * 512]);         \
    gl_lds16(bp + 8 * KDIM,         &dst[16384 + (w * 2 + 1) * 512]);         \
  } while (0)

#define GEMM_BODY(KT, VM, DOSTAGE) do {                                       \
    const unsigned short* sb = &smb[((KT) % 3) * 24576];                      \
    if (DOSTAGE) STAGE_AB((KT) + 2);                                          \
    bf16x8 af0[4], af1[4], bg0[4], bg1[4];                                    \
    _Pragma("unroll")                                                         \
    for (int m_ = 0; m_ < 4; ++m_) {                                          \
      af0[m_] = *(const bf16x8*)&sb[a0 + m_ * 1024];                          \
      af1[m_] = *(const bf16x8*)&sb[a1 + m_ * 1024];                          \
    }                                                                         \
    _Pragma("unroll")                                                         \
    for (int n_ = 0; n_ < 4; ++n_) {                                          \
      bg0[n_] = *(const bf16x8*)&sb[b0 + n_ * 1024];                          \
      bg1[n_] = *(const bf16x8*)&sb[b1 + n_ * 1024];                          \
    }                                                                         \
    asm volatile("s_waitcnt vmcnt(" #VM ")" ::: "memory");                    \
    asm volatile("s_barrier" ::: "memory");                                   \
    asm volatile("s_waitcnt lgkmcnt(0)" ::: "memory");                        \
    __builtin_amdgcn_sched_barrier(0);                                        \
    __builtin_amdgcn_s_setprio(1);                                            \
    _Pragma("unroll")                                                         \
    for (int m_ = 0; m_ < 4; ++m_)                                            \
      _Pragma("unroll")                                                       \
      for (int n_ = 0; n_ < 4; ++n_)                                          \
        acc[m_][n_] = mfma16(af0[m_], bg0[n_], acc[m_][n_]);                  \
    _Pragma("unroll")                                                         \
    for (int m_ = 0; m_ < 4; ++m_)                                            \
      _Pragma("unroll")                                                       \
      for (int n_ = 0; n_ < 4; ++n_)                                          \
        acc[m_][n_] = mfma16(af1[m_], bg1[n_], acc[m_][n_]);                  \
    __builtin_amdgcn_sched_barrier(0);                                        \
    __builtin_amdgcn_s_setprio(0);                                            \
    asm volatile("s_barrier" ::: "memory");                                   \
  } while (0)

#define GEMM_MAIN()                                                           \
  STAGE_AB(0); STAGE_AB(1);                                                   \
  asm volatile("s_waitcnt vmcnt(6)" ::: "memory");                            \
  asm volatile("s_barrier" ::: "memory");                                     \
  _Pragma("unroll 1")                                                         \
  for (int kt = 0; kt < NT64 - 2; ++kt)                                       \
    GEMM_BODY(kt, 6, 1);                                                      \
  GEMM_BODY(NT64 - 2, 0, 0);                                                  \
  GEMM_BODY(NT64 - 1, 0, 0);

// grid: 256 blocks (16 x 16), XCD-swizzled.
__global__ __launch_bounds__(512, 1) void dense_gemm(
    const unsigned short* __restrict__ A,
    const unsigned short* __restrict__ B,
    const float* __restrict__ bias,
    float* __restrict__ out)
{
  __shared__ unsigned short sm[3][24576];   // 144KB
  int id  = blockIdx.x;
  int swz = (id & 7) * (gridDim.x >> 3) + (id >> 3);
  const int m0 = (swz / 16) * 256, n0 = (swz % 16) * 128;
  GEMM_PRE();
  GEMM_MAIN();

  const int g4 = fg * 4;
#pragma unroll
  for (int n = 0; n < 4; ++n) {
    int ncol = n0 + wn * 64 + n * 16 + fr;
    float bv = bias[ncol];
#pragma unroll
    for (int m = 0; m < 4; ++m) {
#pragma unroll
      for (int j = 0; j < 4; ++j) {
        int r = m0 + wm * 64 + m * 16 + g4 + j;
        out[(size_t)r * HID + ncol] = acc[m][n][j] + bv;
      }
    }
  }
}

// =====================================================================
// causal flash attention v2 — occupancy-first.
// grid 1024 = (xcd 8) x (bh-in-xcd 4) x (q-tile 32, dispatched heavy-
// first); block 256 = 4 waves x 16 q-rows (QBLK=64).  KVBLK=32.
// LDS: K double-buffer 2x8KB (swizzled granules) + per-wave P [16][40]
// = 21.3 KB -> with __launch_bounds__(256,3): 3 blocks/CU (12 waves/CU).
// V is NOT staged: 8 bf16x8 fragments read per tile straight from
// Vt[bh][d][s] (L2-resident, 4 bh per XCD = 4MB); issued at iteration
// top so L2 latency hides under QK^T+softmax.  PV's implicit vmcnt wait
// leaves the 2 K-prefetch gl_lds outstanding (V loads issued FIRST).
// =====================================================================

__global__ __launch_bounds__(256, 3) void attn_fwd(
    const unsigned short* __restrict__ Q,
    const unsigned short* __restrict__ K,
    const unsigned short* __restrict__ Vt,   // [bh][d][s]
    unsigned short* __restrict__ ctx)
{
  __shared__ unsigned short Ksh[2][32 * 128];   // 8KB each, swizzled granules
  __shared__ unsigned short Psh[4][16 * 40];    // per-wave P tile, +8 pad
  const int t = threadIdx.x, l = t & 63, w = t >> 6;
  const int id = blockIdx.x;
  const int bh = (id & 7) * 4 + ((id >> 3) & 3);  // 4 bh per XCD (L2 locality)
  const int qt = 31 - (id >> 5);                  // heavy q-tiles dispatch first
  const int fr = l & 15, fg = l >> 4;
  const size_t base  = (size_t)bh * SEQ * HD;
  const size_t vbase = (size_t)bh * HD * SEQ;
  const int NT = 2 * (qt + 1);                    // 32-key tiles

#define STAGE32(BUF, KTT) do {                                                \
    const unsigned short* Kt_ = K + base + (size_t)((KTT) * 32) * HD;         \
    _Pragma("unroll")                                                         \
    for (int i_ = 0; i_ < 2; ++i_) {                                          \
      int ch_  = w * 2 + i_;                                                  \
      int row_ = ch_ * 4 + (l >> 4);                                          \
      int c16_ = (l & 15) ^ (row_ & 7);                                       \
      gl_lds16(Kt_ + (size_t)row_ * HD + c16_ * 8, &Ksh[BUF][ch_ * 512]);     \
    }                                                                         \
  } while (0)

  // Q fragments in registers (scale folded at QKV epilogue)
  bf16x8 qf[4];
  {
    const unsigned short* qp =
        Q + base + (size_t)(qt * 64 + w * 16 + fr) * HD + fg * 8;
#pragma unroll
    for (int c = 0; c < 4; ++c) qf[c] = *(const bf16x8*)(qp + c * 32);
  }
  f32x4 oacc[8] = {};
  float mrow[4] = {-1e30f, -1e30f, -1e30f, -1e30f};
  float lrow[4] = {0.f, 0.f, 0.f, 0.f};

  STAGE32(0, 0);
  __syncthreads();
  int buf = 0;

#pragma unroll 1
  for (int ktt = 0; ktt < NT; ++ktt) {
    // V fragments (global/L2) — issued FIRST so PV's wait keeps K-prefetch flying
    bf16x8 vf[8];
    {
      const unsigned short* vp = Vt + vbase + (size_t)fr * SEQ + ktt * 32 + fg * 8;
#pragma unroll
      for (int n2 = 0; n2 < 8; ++n2)
        vf[n2] = *(const bf16x8*)(vp + (size_t)(n2 * 16) * SEQ);
    }
    if (ktt < NT - 1) STAGE32(buf ^ 1, ktt + 1);   // K prefetch (2 gl_lds/wave)

    // S = Q K^T  (16 q-rows x 32 keys per wave)
    f32x4 sacc[2] = {};
#pragma unroll
    for (int c = 0; c < 4; ++c) {
#pragma unroll
      for (int n = 0; n < 2; ++n) {
        int krow = n * 16 + fr;
        int g_   = (c * 4 + fg) ^ (krow & 7);
        bf16x8 kf = *(const bf16x8*)&Ksh[buf][krow * 128 + g_ * 8];
        sacc[n] = mfma16(qf[c], kf, sacc[n]);
      }
    }
    if (ktt >= 2 * qt) {   // only last two tiles touch the diagonal
#pragma unroll
      for (int n = 0; n < 2; ++n)
#pragma unroll
        for (int j = 0; j < 4; ++j) {
          int key  = ktt * 32 + n * 16 + fr;
          int qrow = qt * 64 + w * 16 + fg * 4 + j;
          if (key > qrow) sacc[n][j] = -1e30f;
        }
    }
    // online softmax over 32 keys
    float tm[4];
#pragma unroll
    for (int j = 0; j < 4; ++j) {
      float v0 = fmaxf(sacc[0][j], sacc[1][j]);
      v0 = fmaxf(v0, __shfl_xor(v0, 1));
      v0 = fmaxf(v0, __shfl_xor(v0, 2));
      v0 = fmaxf(v0, __shfl_xor(v0, 4));
      v0 = fmaxf(v0, __shfl_xor(v0, 8));
      tm[j] = v0;
    }
    float scj[4], psum[4];
#pragma unroll
    for (int j = 0; j < 4; ++j) {
      float mnew = fmaxf(mrow[j], tm[j]);
      scj[j] = exp2f((mrow[j] - mnew) * LOG2E);
      mrow[j] = mnew;
      psum[j] = 0.f;
    }
#pragma unroll
    for (int n = 0; n < 2; ++n)
#pragma unroll
      for (int j = 0; j < 4; ++j) {
        float p = exp2f((sacc[n][j] - mrow[j]) * LOG2E);
        sacc[n][j] = p;
        psum[j] += p;
      }
#pragma unroll
    for (int j = 0; j < 4; ++j) {
      float s = psum[j];
      s += __shfl_xor(s, 1);
      s += __shfl_xor(s, 2);
      s += __shfl_xor(s, 4);
      s += __shfl_xor(s, 8);
      lrow[j] = lrow[j] * scj[j] + s;
    }
#pragma unroll
    for (int n2 = 0; n2 < 8; ++n2)
#pragma unroll
      for (int j = 0; j < 4; ++j)
        oacc[n2][j] *= scj[j];
    // P -> per-wave LDS (same-wave RAW; compiler orders via lgkmcnt)
#pragma unroll
    for (int n = 0; n < 2; ++n)
#pragma unroll
      for (int j = 0; j < 4; ++j)
        Psh[w][(fg * 4 + j) * 40 + n * 16 + fr] = f2bf(sacc[n][j]);
    bf16x8 pf = *(const bf16x8*)&Psh[w][fr * 40 + fg * 8];
    // O += P V  (k = 32 keys = one MFMA k-slab)
#pragma unroll
    for (int n2 = 0; n2 < 8; ++n2)
      oacc[n2] = mfma16(pf, vf[n2], oacc[n2]);
    __syncthreads();          // drains K prefetch; next buf ready
    buf ^= 1;
  }

  // normalize + write ctx[(s*B+b)][h*128+d] bf16
  const int bb = bh >> 4, h = bh & 15;
#pragma unroll
  for (int n2 = 0; n2 < 8; ++n2)
#pragma unroll
    for (int j = 0; j < 4; ++j) {
      int qrow = qt * 64 + w * 16 + fg * 4 + j;
      float val = oacc[n2][j] / lrow[j];
      ctx[((size_t)(qrow * BATCH + bb)) * HID + h * HD + n2 * 16 + fr] = f2bf(val);
    }
#undef STAGE32
}

// ---------------- launcher ----------------
extern "C" void kernel_launch(void* const* d_in, const int* in_sizes, int n_in,
                              void* d_out, int out_size, void* d_ws, size_t ws_size,
                              hipStream_t stream) {
  const float* hs      = (const float*)d_in[0];
  const float* w_qkv   = (const float*)d_in[1];
  const float* b_qkv   = (const float*)d_in[2];
  const float* w_dense = (const float*)d_in[3];
  const float* b_dense = (const float*)d_in[4];
  float* out = (float*)d_out;

  unsigned short* hsb = (unsigned short*)d_ws;              // 8.4M shorts
  unsigned short* wqb = hsb + (size_t)MTOT * HID;
  unsigned short* wdb = wqb + (size_t)NQKV * HID;
  unsigned short* q   = wdb + (size_t)HID * HID;
  unsigned short* k   = q   + (size_t)MTOT * HID;
  unsigned short* v   = k   + (size_t)MTOT * HID;
  unsigned short* ctx = v   + (size_t)MTOT * HID;
  unsigned short* vt  = hsb;   // alias: hsb dead after qkv_gemm, vt written before attn

  cvt3_f32_bf16<<<2048, 256, 0, stream>>>(
      hs, hsb, (MTOT * HID) / 4,
      w_qkv, wqb, (NQKV * HID) / 4,
      w_dense, wdb, (HID * HID) / 4);

  qkv_gemm<<<dim3((MTOT / 256) * (NQKV / 192)), 512, 0, stream>>>(hsb, wqb, b_qkv, q, k, v);
  transpose_v<<<dim3(SEQ / 64, HD / 64, BATCH * NH), 256, 0, stream>>>(v, vt);
  attn_fwd<<<1024, 256, 0, stream>>>(q, k, vt, ctx);
  dense_gemm<<<dim3((MTOT / 256) * (HID / 128)), 512, 0, stream>>>(ctx, wdb, b_dense, out);
}

// Round 11
// 282.113 us; speedup vs baseline: 1.1759x; 1.1759x over previous
//
#include <hip/hip_runtime.h>
#include <stdint.h>
#include <stddef.h>

// ---------------- problem constants ----------------
#define SEQ   2048
#define BATCH 2
#define HID   2048
#define NH    16
#define HD    128
#define MTOT  (SEQ*BATCH)   // 4096
#define NQKV  (3*HID)       // 6144
#define KDIM  HID           // 2048
#define LOG2E 1.4426950408889634f

#define BK64    64
#define NT64    (KDIM/BK64)   // 32

typedef short  bf16x8 __attribute__((ext_vector_type(8)));  // 8 bf16 in 4 VGPRs
typedef float  f32x4  __attribute__((ext_vector_type(4)));

__device__ __forceinline__ unsigned short f2bf(float f) {
  union { float f; uint32_t u; } a; a.f = f;
  uint32_t r = a.u + 0x7fffu + ((a.u >> 16) & 1u);   // RNE
  return (unsigned short)(r >> 16);
}

__device__ __forceinline__ f32x4 mfma16(bf16x8 a, bf16x8 b, f32x4 c) {
  return __builtin_amdgcn_mfma_f32_16x16x32_bf16(a, b, c, 0, 0, 0);
}

// async global->LDS, 16B per lane; LDS dest = wave-uniform base + lane*16
__device__ __forceinline__ void gl_lds16(const unsigned short* g, unsigned short* l) {
  __builtin_amdgcn_global_load_lds(
      (const __attribute__((address_space(1))) void*)g,
      (__attribute__((address_space(3))) void*)l, 16, 0, 0);
}

// ---------------- fused fp32 -> bf16 convert (3 tensors, 1 launch) ----------------
__global__ void cvt3_f32_bf16(const float* __restrict__ a, unsigned short* __restrict__ oa, int na,
                              const float* __restrict__ b, unsigned short* __restrict__ ob, int nb,
                              const float* __restrict__ c, unsigned short* __restrict__ oc, int nc) {
  int i = blockIdx.x * blockDim.x + threadIdx.x;
  int stride = gridDim.x * blockDim.x;
  int ntot = na + nb + nc;
  for (; i < ntot; i += stride) {
    const float* src; unsigned short* dst; int j;
    if (i < na)           { src = a; dst = oa; j = i; }
    else if (i < na + nb) { src = b; dst = ob; j = i - na; }
    else                  { src = c; dst = oc; j = i - na - nb; }
    float4 f = reinterpret_cast<const float4*>(src)[j];
    ushort4 o;
    o.x = f2bf(f.x); o.y = f2bf(f.y); o.z = f2bf(f.z); o.w = f2bf(f.w);
    reinterpret_cast<ushort4*>(dst)[j] = o;
  }
}

// =====================================================================
// 8-phase 256x192 GEMM (qkv): BK=64, 512 thr = 8 waves (2M x 4N),
// per-wave output 128x48 (acc[8][3] = 96 VGPR).
// Grid 16 x 32 = 512 blocks = EXACTLY 2 full dispatch waves (no tail).
// LDS: 2 buffers x 56KB (A 256x64 @0, B 192x64 @16384 shorts).
// Swizzle (involution, 16B granules): LDS[r][g] = glob[r][g ^ (r&7)].
// Per K-tile: 4 phases; phase G computes m-frags {2G,2G+1} x 3n x 2k
// = 12 MFMA. Staging of tile t+1 (7 gloads/wave, issue order):
//   ph0: B0,B64   ph1: B128,A0   ph2: A128,A64   ph3: A192
// Counted waits: ph1 vmcnt(4) retires A64,A192(t) before ph2 reads;
// ph3 vmcnt(2) retires B*,A0,A128(t+1) before ph0(t+1), leaving
// A64,A192(t+1) in flight. Never vmcnt(0) in steady state.
// V is written TRANSPOSED [bh][d][s] directly from the epilogue.
// Measured: 120 us = 857 TF = the m97-structure plain-HIP ceiling
// (rounds 7-9 tried read-ahead / free-flow / m201-quadrant schedules:
// all 128-158 us; this phase structure is the best of six variants).
// =====================================================================

#define QBUFS 28672   // shorts per LDS buffer: A 16384 + B 12288

#define QSTA(R) gl_lds16(Asrc + (size_t)(R) * KDIM + koff, &db[((R) + w * 8) * 64])
#define QSTB(R) gl_lds16(Bsrc + (size_t)(R) * KDIM + koff, &db[16384 + ((R) + w * 8) * 64])

#define G8_SB()  asm volatile("s_barrier" ::: "memory")
#define G8_LGKM() do { asm volatile("s_waitcnt lgkmcnt(0)" ::: "memory");     \
                       __builtin_amdgcn_sched_barrier(0); } while (0)

#define G8_RDA(G) do {                                                        \
    p0 = *(const bf16x8*)&sb[abase + (2*(G)    ) * 1024 + ga0];               \
    p1 = *(const bf16x8*)&sb[abase + (2*(G)    ) * 1024 + ga1];               \
    p2 = *(const bf16x8*)&sb[abase + (2*(G) + 1) * 1024 + ga0];               \
    p3 = *(const bf16x8*)&sb[abase + (2*(G) + 1) * 1024 + ga1];               \
  } while (0)

#define G8_MFMA(G) do {                                                       \
    __builtin_amdgcn_s_setprio(1);                                            \
    _Pragma("unroll")                                                         \
    for (int n_ = 0; n_ < 3; ++n_) {                                          \
      acc[2*(G)][n_]     = mfma16(p0, bq0[n_], acc[2*(G)][n_]);               \
      acc[2*(G)][n_]     = mfma16(p1, bq1[n_], acc[2*(G)][n_]);               \
      acc[2*(G) + 1][n_] = mfma16(p2, bq0[n_], acc[2*(G) + 1][n_]);           \
      acc[2*(G) + 1][n_] = mfma16(p3, bq1[n_], acc[2*(G) + 1][n_]);           \
    }                                                                         \
    __builtin_amdgcn_sched_barrier(0);                                        \
    __builtin_amdgcn_s_setprio(0);                                            \
  } while (0)

#define G8_TILE(DOSTAGE, VM1, VM3) do {                                       \
    bf16x8 bq0[3], bq1[3], p0, p1, p2, p3;                                    \
    /* ---- phase 0 ---- */                                                   \
    _Pragma("unroll")                                                         \
    for (int n_ = 0; n_ < 3; ++n_) {                                          \
      bq0[n_] = *(const bf16x8*)&sb[bbase + n_ * 1024 + ga0];                 \
      bq1[n_] = *(const bf16x8*)&sb[bbase + n_ * 1024 + ga1];                 \
    }                                                                         \
    G8_RDA(0);                                                                \
    if (DOSTAGE) { QSTB(0); QSTB(64); }                                       \
    G8_SB(); G8_LGKM();                                                       \
    G8_MFMA(0);                                                               \
    G8_SB();                                                                  \
    /* ---- phase 1 ---- */                                                   \
    G8_RDA(1);                                                                \
    if (DOSTAGE) { QSTB(128); QSTA(0); }                                      \
    asm volatile("s_waitcnt " VM1 ::: "memory");                              \
    G8_SB(); G8_LGKM();                                                       \
    G8_MFMA(1);                                                               \
    G8_SB();                                                                  \
    /* ---- phase 2 ---- */                                                   \
    G8_RDA(2);                                                                \
    if (DOSTAGE) { QSTA(128); QSTA(64); }                                     \
    G8_SB(); G8_LGKM();                                                       \
    G8_MFMA(2);                                                               \
    G8_SB();                                                                  \
    /* ---- phase 3 ---- */                                                   \
    G8_RDA(3);                                                                \
    if (DOSTAGE) { QSTA(192); }                                               \
    asm volatile("s_waitcnt " VM3 ::: "memory");                              \
    G8_SB(); G8_LGKM();                                                       \
    G8_MFMA(3);                                                               \
    G8_SB();                                                                  \
  } while (0)

// grid: 512 blocks (16 m x 32 n), XCD-swizzled (512 % 8 == 0).
__global__ __launch_bounds__(512, 2) void qkv_gemm(
    const unsigned short* __restrict__ A,
    const unsigned short* __restrict__ B,
    const float* __restrict__ bias,
    unsigned short* __restrict__ Qo,
    unsigned short* __restrict__ Ko,
    unsigned short* __restrict__ Vt)      // V written TRANSPOSED [bh][d][s]
{
  __shared__ unsigned short smb[2 * QBUFS];   // 112 KB
  const int id  = blockIdx.x;
  const int swz = (id & 7) * 64 + (id >> 3);
  const int m0 = (swz >> 5) * 256, n0 = (swz & 31) * 192;
  const int t = threadIdx.x, l = t & 63, w = t >> 6;
  const int wm = w >> 2, wn = w & 3;
  const int fr = l & 15, fg = l >> 4;
  const int abase = (wm * 128 + fr) * 64;
  const int bbase = 16384 + (wn * 48 + fr) * 64;
  const int ga0 = ((fg     ) ^ (fr & 7)) * 8;
  const int ga1 = ((fg + 4 ) ^ (fr & 7)) * 8;
  const int srcrow = w * 8 + (l >> 3);
  const int sgr    = ((l & 7) ^ (l >> 3)) * 8;
  const unsigned short* Asrc = A + (size_t)(m0 + srcrow) * KDIM + sgr;
  const unsigned short* Bsrc = B + (size_t)(n0 + srcrow) * KDIM + sgr;
  f32x4 acc[8][3] = {};

  { // prologue: stage tile 0 (order: B0,B64,B128,A0,A128,A64,A192)
    unsigned short* db = smb;
    size_t koff = 0;
    QSTB(0); QSTB(64); QSTB(128);
    QSTA(0); QSTA(128); QSTA(64); QSTA(192);
  }
  asm volatile("s_waitcnt vmcnt(2)" ::: "memory");   // A64,A192 still in flight
  asm volatile("s_barrier" ::: "memory");

#pragma unroll 1
  for (int kt = 0; kt < NT64 - 1; ++kt) {
    const unsigned short* sb = &smb[(kt & 1) * QBUFS];
    unsigned short* db = &smb[((kt + 1) & 1) * QBUFS];
    size_t koff = (size_t)(kt + 1) * BK64;
    G8_TILE(1, "vmcnt(4)", "vmcnt(2)");
  }
  { // last tile: no staging; drain remaining A64,A192 at ph1
    const unsigned short* sb = &smb[((NT64 - 1) & 1) * QBUFS];
    unsigned short* db = smb;    // unused (DOSTAGE=0)
    size_t koff = 0; (void)koff;
    G8_TILE(0, "vmcnt(0)", "vmcnt(0)");
  }

  // epilogue: bias (+ q-scale fold); Q,K -> [b][h][s][d]; V -> [b][h][d][s]
#pragma unroll
  for (int n = 0; n < 3; ++n) {
    int ncol = n0 + wn * 48 + n * 16 + fr;
    float bv = bias[ncol];
    int head = ncol / 384;
    int rem  = ncol - head * 384;
    int wi   = rem >> 7;          // 0=q 1=k 2=v
    int d    = rem & 127;
#pragma unroll
    for (int m = 0; m < 8; ++m) {
#pragma unroll
      for (int j = 0; j < 4; ++j) {
        int r = m0 + wm * 128 + m * 16 + fg * 4 + j;
        int s = r >> 1, bb = r & 1;
        float val = acc[m][n][j] + bv;
        if (wi == 0) {
          val *= 0.08838834764831845f;   // fold 1/sqrt(128) into Q
          Qo[(((size_t)(bb * NH + head)) * SEQ + s) * HD + d] = f2bf(val);
        } else if (wi == 1) {
          Ko[(((size_t)(bb * NH + head)) * SEQ + s) * HD + d] = f2bf(val);
        } else {
          Vt[(((size_t)(bb * NH + head)) * HD + d) * SEQ + s] = f2bf(val);
        }
      }
    }
  }
}

// =====================================================================
// dense GEMM: BM=256, BN=128, BK=64, 3-buf rotation (round-4 structure)
// =====================================================================

#define GEMM_PRE()                                                            \
  const int t = threadIdx.x, l = t & 63, w = t >> 6;                          \
  const int wm = w >> 1, wn = w & 1;                                          \
  const int fr = l & 15, fg = l >> 4;                                         \
  const int fx = fr & 7;                                                      \
  const int srow = l >> 3;                                                    \
  const int sgr  = ((l & 7) ^ srow) * 8;                                      \
  const unsigned short* Aw = A + (size_t)(m0 + w * 32 + srow) * KDIM + sgr;   \
  const unsigned short* Bw = B + (size_t)(n0 + w * 16 + srow) * KDIM + sgr;   \
  unsigned short* smb = &sm[0][0];                                            \
  const int a0 = (wm * 64 + fr) * 64 + ((fg ^ fx) * 8);                       \
  const int a1 = (wm * 64 + fr) * 64 + (((4 + fg) ^ fx) * 8);                 \
  const int b0 = 16384 + (wn * 64 + fr) * 64 + ((fg ^ fx) * 8);               \
  const int b1 = 16384 + (wn * 64 + fr) * 64 + (((4 + fg) ^ fx) * 8);         \
  f32x4 acc[4][4] = {};

#define STAGE_AB(KT) do {                                                     \
    unsigned short* dst = &smb[((KT) % 3) * 24576];                           \
    const unsigned short* ap = Aw + (size_t)(KT) * BK64;                      \
    gl_lds16(ap,                    &dst[(w * 4 + 0) * 512]);                 \
    gl_lds16(ap + 8  * KDIM,        &dst[(w * 4 + 1) * 512]);                 \
    gl_lds16(ap + 16 * KDIM,        &dst[(w * 4 + 2) * 512]);                 \
    gl_lds16(ap + 24 * KDIM,        &dst[(w * 4 + 3) * 512]);                 \
    const unsigned short* bp = Bw + (size_t)(KT) * BK64;                      \
    gl_lds16(bp,                    &dst[16384 + (w * 2 + 0) * 512]);         \
    gl_lds16(bp + 8 * KDIM,         &dst[16384 + (w * 2 + 1) * 512]);         \
  } while (0)

#define GEMM_BODY(KT, VM, DOSTAGE) do {                                       \
    const unsigned short* sb = &smb[((KT) % 3) * 24576];                      \
    if (DOSTAGE) STAGE_AB((KT) + 2);                                          \
    bf16x8 af0[4], af1[4], bg0[4], bg1[4];                                    \
    _Pragma("unroll")                                                         \
    for (int m_ = 0; m_ < 4; ++m_) {                                          \
      af0[m_] = *(const bf16x8*)&sb[a0 + m_ * 1024];                          \
      af1[m_] = *(const bf16x8*)&sb[a1 + m_ * 1024];                          \
    }                                                                         \
    _Pragma("unroll")                                                         \
    for (int n_ = 0; n_ < 4; ++n_) {                                          \
      bg0[n_] = *(const bf16x8*)&sb[b0 + n_ * 1024];                          \
      bg1[n_] = *(const bf16x8*)&sb[b1 + n_ * 1024];                          \
    }                                                                         \
    asm volatile("s_waitcnt vmcnt(" #VM ")" ::: "memory");                    \
    asm volatile("s_barrier" ::: "memory");                                   \
    asm volatile("s_waitcnt lgkmcnt(0)" ::: "memory");                        \
    __builtin_amdgcn_sched_barrier(0);                                        \
    __builtin_amdgcn_s_setprio(1);                                            \
    _Pragma("unroll")                                                         \
    for (int m_ = 0; m_ < 4; ++m_)                                            \
      _Pragma("unroll")                                                       \
      for (int n_ = 0; n_ < 4; ++n_)                                          \
        acc[m_][n_] = mfma16(af0[m_], bg0[n_], acc[m_][n_]);                  \
    _Pragma("unroll")                                                         \
    for (int m_ = 0; m_ < 4; ++m_)                                            \
      _Pragma("unroll")                                                       \
      for (int n_ = 0; n_ < 4; ++n_)                                          \
        acc[m_][n_] = mfma16(af1[m_], bg1[n_], acc[m_][n_]);                  \
    __builtin_amdgcn_sched_barrier(0);                                        \
    __builtin_amdgcn_s_setprio(0);                                            \
    asm volatile("s_barrier" ::: "memory");                                   \
  } while (0)

#define GEMM_MAIN()                                                           \
  STAGE_AB(0); STAGE_AB(1);                                                   \
  asm volatile("s_waitcnt vmcnt(6)" ::: "memory");                            \
  asm volatile("s_barrier" ::: "memory");                                     \
  _Pragma("unroll 1")                                                         \
  for (int kt = 0; kt < NT64 - 2; ++kt)                                       \
    GEMM_BODY(kt, 6, 1);                                                      \
  GEMM_BODY(NT64 - 2, 0, 0);                                                  \
  GEMM_BODY(NT64 - 1, 0, 0);

// grid: 256 blocks (16 x 16), XCD-swizzled.
__global__ __launch_bounds__(512, 1) void dense_gemm(
    const unsigned short* __restrict__ A,
    const unsigned short* __restrict__ B,
    const float* __restrict__ bias,
    float* __restrict__ out)
{
  __shared__ unsigned short sm[3][24576];   // 144KB
  int id  = blockIdx.x;
  int swz = (id & 7) * (gridDim.x >> 3) + (id >> 3);
  const int m0 = (swz / 16) * 256, n0 = (swz % 16) * 128;
  GEMM_PRE();
  GEMM_MAIN();

  const int g4 = fg * 4;
#pragma unroll
  for (int n = 0; n < 4; ++n) {
    int ncol = n0 + wn * 64 + n * 16 + fr;
    float bv = bias[ncol];
#pragma unroll
    for (int m = 0; m < 4; ++m) {
#pragma unroll
      for (int j = 0; j < 4; ++j) {
        int r = m0 + wm * 64 + m * 16 + g4 + j;
        out[(size_t)r * HID + ncol] = acc[m][n][j] + bv;
      }
    }
  }
}

// ---------------- causal flash attention, paired q-tiles ----------------
// grid (16 pairs, 32 bh); block 256 = 4 waves x 16 q-rows per tile.
// Block handles q-tiles {pair, 31-pair}: exactly 33 tile-computes each.
__global__ __launch_bounds__(256, 2) void attn_fwd(
    const unsigned short* __restrict__ Q,
    const unsigned short* __restrict__ K,
    const unsigned short* __restrict__ Vt,   // [bh][d][s]
    unsigned short* __restrict__ ctx)
{
  __shared__ unsigned short Ksh[2][64 * 128];   // swizzled granules, 16KB each
  __shared__ unsigned short Vsh[2][128 * 64];   // [d][key] swizzled, 16KB each
  __shared__ unsigned short Psh[4][16 * 72];    // per-wave P tile
  const int t = threadIdx.x, l = t & 63, w = t >> 6;
  int nwg = gridDim.x * gridDim.y;              // 512
  int id  = blockIdx.y * gridDim.x + blockIdx.x;
  int swz = (id & 7) * (nwg >> 3) + (id >> 3);
  const int pair = swz & 15;
  const int bh   = swz >> 4;
  const int qtA = pair, qtB = 31 - pair;
  const int fr = l & 15, fg = l >> 4;
  const size_t base  = (size_t)bh * SEQ * HD;
  const size_t vbase = (size_t)bh * HD * SEQ;

#define STAGE(BUF, KT) do {                                                   \
    const unsigned short* Kt_ = K + base + (size_t)((KT) * 64) * HD;          \
    _Pragma("unroll")                                                         \
    for (int i_ = 0; i_ < 4; ++i_) {                                          \
      int ch_  = w * 4 + i_;                                                  \
      int row_ = ch_ * 4 + (l >> 4);                                          \
      int c16_ = (l & 15) ^ (row_ & 7);                                       \
      gl_lds16(Kt_ + (size_t)row_ * HD + c16_ * 8, &Ksh[BUF][ch_ * 512]);     \
    }                                                                         \
    const unsigned short* Vg_ = Vt + vbase + (KT) * 64;                       \
    _Pragma("unroll")                                                         \
    for (int i_ = 0; i_ < 4; ++i_) {                                          \
      int ch_  = w * 4 + i_;                                                  \
      int row_ = ch_ * 8 + (l >> 3);                                          \
      int c16_ = (l & 7) ^ (row_ & 7);                                        \
      gl_lds16(Vg_ + (size_t)row_ * SEQ + c16_ * 8, &Vsh[BUF][ch_ * 512]);    \
    }                                                                         \
  } while (0)

#define COMPUTE_TILE(QF, OACC, MROW, LROW, QT) do {                           \
    f32x4 sacc[4] = {};                                                       \
    _Pragma("unroll")                                                         \
    for (int c_ = 0; c_ < 4; ++c_) {                                          \
      _Pragma("unroll")                                                       \
      for (int n_ = 0; n_ < 4; ++n_) {                                        \
        int krow = n_ * 16 + fr;                                              \
        int g_   = (c_ * 4 + fg) ^ (krow & 7);                                \
        bf16x8 kf = *(const bf16x8*)&Ksh[buf][krow * 128 + g_ * 8];           \
        sacc[n_] = mfma16(QF[c_], kf, sacc[n_]);                              \
      }                                                                       \
    }                                                                         \
    if (kt == (QT)) {                                                         \
      _Pragma("unroll")                                                       \
      for (int n_ = 0; n_ < 4; ++n_)                                          \
        _Pragma("unroll")                                                     \
        for (int j_ = 0; j_ < 4; ++j_)                                        \
          if (n_ * 16 + fr > w * 16 + fg * 4 + j_) sacc[n_][j_] = -1e30f;     \
    }                                                                         \
    float tm_[4];                                                             \
    _Pragma("unroll")                                                         \
    for (int j_ = 0; j_ < 4; ++j_) {                                          \
      float v0 = fmaxf(fmaxf(sacc[0][j_], sacc[1][j_]),                       \
                       fmaxf(sacc[2][j_], sacc[3][j_]));                      \
      v0 = fmaxf(v0, __shfl_xor(v0, 1));                                      \
      v0 = fmaxf(v0, __shfl_xor(v0, 2));                                      \
      v0 = fmaxf(v0, __shfl_xor(v0, 4));                                      \
      v0 = fmaxf(v0, __shfl_xor(v0, 8));                                      \
      tm_[j_] = v0;                                                           \
    }                                                                         \
    float sc_[4], ps_[4];                                                     \
    _Pragma("unroll")                                                         \
    for (int j_ = 0; j_ < 4; ++j_) {                                          \
      float mn_ = fmaxf(MROW[j_], tm_[j_]);                                   \
      sc_[j_] = exp2f((MROW[j_] - mn_) * LOG2E);                              \
      MROW[j_] = mn_;                                                         \
      ps_[j_] = 0.f;                                                          \
    }                                                                         \
    _Pragma("unroll")                                                         \
    for (int n_ = 0; n_ < 4; ++n_)                                            \
      _Pragma("unroll")                                                       \
      for (int j_ = 0; j_ < 4; ++j_) {                                        \
        float p_ = exp2f((sacc[n_][j_] - MROW[j_]) * LOG2E);                  \
        sacc[n_][j_] = p_;                                                    \
        ps_[j_] += p_;                                                        \
      }                                                                       \
    _Pragma("unroll")                                                         \
    for (int j_ = 0; j_ < 4; ++j_) {                                          \
      float s_ = ps_[j_];                                                     \
      s_ += __shfl_xor(s_, 1);                                                \
      s_ += __shfl_xor(s_, 2);                                                \
      s_ += __shfl_xor(s_, 4);                                                \
      s_ += __shfl_xor(s_, 8);                                                \
      LROW[j_] = LROW[j_] * sc_[j_] + s_;                                     \
    }                                                                         \
    _Pragma("unroll")                                                         \
    for (int n_ = 0; n_ < 8; ++n_)                                            \
      _Pragma("unroll")                                                       \
      for (int j_ = 0; j_ < 4; ++j_)                                          \
        OACC[n_][j_] *= sc_[j_];                                              \
    _Pragma("unroll")                                                         \
    for (int n_ = 0; n_ < 4; ++n_)                                            \
      _Pragma("unroll")                                                       \
      for (int j_ = 0; j_ < 4; ++j_)                                          \
        Psh[w][(fg * 4 + j_) * 72 + n_ * 16 + fr] = f2bf(sacc[n_][j_]);       \
    _Pragma("unroll")                                                         \
    for (int ks_ = 0; ks_ < 2; ++ks_) {                                       \
      bf16x8 pf = *(const bf16x8*)&Psh[w][fr * 72 + ks_ * 32 + fg * 8];       \
      _Pragma("unroll")                                                       \
      for (int n_ = 0; n_ < 8; ++n_) {                                        \
        int vrow = n_ * 16 + fr;                                              \
        int g_   = (ks_ * 4 + fg) ^ (vrow & 7);                               \
        bf16x8 vf = *(const bf16x8*)&Vsh[buf][vrow * 64 + g_ * 8];            \
        OACC[n_] = mfma16(pf, vf, OACC[n_]);                                  \
      }                                                                       \
    }                                                                         \
  } while (0)

  // Q fragments for both tiles (scale folded in at QKV epilogue)
  bf16x8 qfA[4], qfB[4];
  {
    const unsigned short* qpA = Q + base + (size_t)(qtA * 64 + w * 16 + fr) * HD + fg * 8;
    const unsigned short* qpB = Q + base + (size_t)(qtB * 64 + w * 16 + fr) * HD + fg * 8;
#pragma unroll
    for (int c = 0; c < 4; ++c) {
      qfA[c] = *(const bf16x8*)(qpA + c * 32);
      qfB[c] = *(const bf16x8*)(qpB + c * 32);
    }
  }
  f32x4 oaccA[8] = {}, oaccB[8] = {};
  float mA[4] = {-1e30f, -1e30f, -1e30f, -1e30f};
  float mB[4] = {-1e30f, -1e30f, -1e30f, -1e30f};
  float lA[4] = {0.f, 0.f, 0.f, 0.f};
  float lB[4] = {0.f, 0.f, 0.f, 0.f};

  STAGE(0, 0);
  __syncthreads();
  int buf = 0;
  for (int kt = 0; kt <= qtB; ++kt) {
    if (kt < qtB) STAGE(buf ^ 1, kt + 1);       // prefetch hides under compute
    COMPUTE_TILE(qfB, oaccB, mB, lB, qtB);
    if (kt <= qtA) COMPUTE_TILE(qfA, oaccA, mA, lA, qtA);
    __syncthreads();                            // drains vmcnt -> next buf ready
    buf ^= 1;
  }

  const int bb = bh >> 4, h = bh & 15;
#define WRITE_CTX(OACC, LROW, QT) do {                                        \
    _Pragma("unroll")                                                         \
    for (int n_ = 0; n_ < 8; ++n_)                                            \
      _Pragma("unroll")                                                       \
      for (int j_ = 0; j_ < 4; ++j_) {                                        \
        int qrow = (QT) * 64 + w * 16 + fg * 4 + j_;                          \
        float val = OACC[n_][j_] / LROW[j_];                                  \
        ctx[((size_t)(qrow * BATCH + bb)) * HID + h * HD + n_ * 16 + fr] =    \
            f2bf(val);                                                        \
      }                                                                       \
  } while (0)
  WRITE_CTX(oaccA, lA, qtA);
  WRITE_CTX(oaccB, lB, qtB);
#undef STAGE
#undef COMPUTE_TILE
#undef WRITE_CTX
}

// ---------------- launcher ----------------
extern "C" void kernel_launch(void* const* d_in, const int* in_sizes, int n_in,
                              void* d_out, int out_size, void* d_ws, size_t ws_size,
                              hipStream_t stream) {
  const float* hs      = (const float*)d_in[0];
  const float* w_qkv   = (const float*)d_in[1];
  const float* b_qkv   = (const float*)d_in[2];
  const float* w_dense = (const float*)d_in[3];
  const float* b_dense = (const float*)d_in[4];
  float* out = (float*)d_out;

  unsigned short* hsb = (unsigned short*)d_ws;              // 8.4M shorts
  unsigned short* wqb = hsb + (size_t)MTOT * HID;
  unsigned short* wdb = wqb + (size_t)NQKV * HID;
  unsigned short* q   = wdb + (size_t)HID * HID;
  unsigned short* k   = q   + (size_t)MTOT * HID;
  unsigned short* vt  = k   + (size_t)MTOT * HID;           // V transposed [bh][d][s]
  unsigned short* ctx = vt  + (size_t)MTOT * HID;

  cvt3_f32_bf16<<<2048, 256, 0, stream>>>(
      hs, hsb, (MTOT * HID) / 4,
      w_qkv, wqb, (NQKV * HID) / 4,
      w_dense, wdb, (HID * HID) / 4);

  qkv_gemm<<<dim3((MTOT / 256) * (NQKV / 192)), 512, 0, stream>>>(hsb, wqb, b_qkv, q, k, vt);
  attn_fwd<<<dim3(16, 32), 256, 0, stream>>>(q, k, vt, ctx);
  dense_gemm<<<dim3((MTOT / 256) * (HID / 128)), 512, 0, stream>>>(ctx, wdb, b_dense, out);
}

// Round 12
// 274.733 us; speedup vs baseline: 1.2074x; 1.0269x over previous
//
#include <hip/hip_runtime.h>
#include <stdint.h>
#include <stddef.h>

// ---------------- problem constants ----------------
#define SEQ   2048
#define BATCH 2
#define HID   2048
#define NH    16
#define HD    128
#define MTOT  (SEQ*BATCH)   // 4096
#define NQKV  (3*HID)       // 6144
#define KDIM  HID           // 2048
#define LOG2E 1.4426950408889634f

#define BK64    64
#define NT64    (KDIM/BK64)   // 32

typedef short  bf16x8 __attribute__((ext_vector_type(8)));  // 8 bf16 in 4 VGPRs
typedef float  f32x4  __attribute__((ext_vector_type(4)));

__device__ __forceinline__ unsigned short f2bf(float f) {
  union { float f; uint32_t u; } a; a.f = f;
  uint32_t r = a.u + 0x7fffu + ((a.u >> 16) & 1u);   // RNE
  return (unsigned short)(r >> 16);
}

__device__ __forceinline__ f32x4 mfma16(bf16x8 a, bf16x8 b, f32x4 c) {
  return __builtin_amdgcn_mfma_f32_16x16x32_bf16(a, b, c, 0, 0, 0);
}

// async global->LDS, 16B per lane; LDS dest = wave-uniform base + lane*16
__device__ __forceinline__ void gl_lds16(const unsigned short* g, unsigned short* l) {
  __builtin_amdgcn_global_load_lds(
      (const __attribute__((address_space(1))) void*)g,
      (__attribute__((address_space(3))) void*)l, 16, 0, 0);
}

// ---------------- fused fp32 -> bf16 convert (3 tensors, 1 launch) ----------------
__global__ void cvt3_f32_bf16(const float* __restrict__ a, unsigned short* __restrict__ oa, int na,
                              const float* __restrict__ b, unsigned short* __restrict__ ob, int nb,
                              const float* __restrict__ c, unsigned short* __restrict__ oc, int nc) {
  int i = blockIdx.x * blockDim.x + threadIdx.x;
  int stride = gridDim.x * blockDim.x;
  int ntot = na + nb + nc;
  for (; i < ntot; i += stride) {
    const float* src; unsigned short* dst; int j;
    if (i < na)           { src = a; dst = oa; j = i; }
    else if (i < na + nb) { src = b; dst = ob; j = i - na; }
    else                  { src = c; dst = oc; j = i - na - nb; }
    float4 f = reinterpret_cast<const float4*>(src)[j];
    ushort4 o;
    o.x = f2bf(f.x); o.y = f2bf(f.y); o.z = f2bf(f.z); o.w = f2bf(f.w);
    reinterpret_cast<ushort4*>(dst)[j] = o;
  }
}

// ---------------- V transpose: [bh][s][d] -> [bh][d][s] ----------------
// Coalesced via LDS tile; ~10 us.  Measured round 11: fusing this as a
// transposed scatter into qkv's epilogue costs qkv +55 us (2B/lane at
// 4KB stride) — keep the dedicated kernel.
__global__ __launch_bounds__(256) void transpose_v(
    const unsigned short* __restrict__ V, unsigned short* __restrict__ Vt) {
  __shared__ unsigned short tile[64][72];
  const int t  = threadIdx.x;
  const int bh = blockIdx.z;
  const int s0 = blockIdx.x * 64;
  const int d0 = blockIdx.y * 64;
  const size_t vb = (size_t)bh * SEQ * HD;
  const size_t tb = (size_t)bh * HD * SEQ;
#pragma unroll
  for (int p = 0; p < 2; ++p) {
    int r = p * 32 + (t >> 3);
    *(uint4*)&tile[r][(t & 7) * 8] =
        *(const uint4*)&V[vb + (size_t)(s0 + r) * HD + d0 + (t & 7) * 8];
  }
  __syncthreads();
#pragma unroll
  for (int p = 0; p < 2; ++p) {
    int dr = p * 32 + (t >> 3);
    int sc = (t & 7) * 8;
    unsigned short tmp[8];
#pragma unroll
    for (int e = 0; e < 8; ++e) tmp[e] = tile[sc + e][dr];
    *(uint4*)&Vt[tb + (size_t)(d0 + dr) * SEQ + s0 + sc] = *(const uint4*)tmp;
  }
}

// =====================================================================
// 8-phase 256x192 GEMM (qkv): BK=64, 512 thr = 8 waves (2M x 4N),
// per-wave output 128x48 (acc[8][3] = 96 VGPR).
// Grid 16 x 32 = 512 blocks = EXACTLY 2 full dispatch waves (no tail).
// LDS: 2 buffers x 56KB (A 256x64 @0, B 192x64 @16384 shorts).
// Swizzle (involution, 16B granules): LDS[r][g] = glob[r][g ^ (r&7)].
// Per K-tile: 4 phases; phase G computes m-frags {2G,2G+1} x 3n x 2k
// = 12 MFMA. Staging of tile t+1 (7 gloads/wave, issue order):
//   ph0: B0,B64   ph1: B128,A0   ph2: A128,A64   ph3: A192
// Counted waits: ph1 vmcnt(4) retires A64,A192(t) before ph2 reads;
// ph3 vmcnt(2) retires B*,A0,A128(t+1) before ph0(t+1), leaving
// A64,A192(t+1) in flight. Never vmcnt(0) in steady state.
// Measured (round 6): 120 us = 857 TF, MfmaUtil 37.6%, conflicts 0 —
// the plain-HIP ceiling for this structure (6 schedule variants tried
// in rounds 7-9 all regressed: 128-175 us).
// =====================================================================

#define QBUFS 28672   // shorts per LDS buffer: A 16384 + B 12288

#define QSTA(R) gl_lds16(Asrc + (size_t)(R) * KDIM + koff, &db[((R) + w * 8) * 64])
#define QSTB(R) gl_lds16(Bsrc + (size_t)(R) * KDIM + koff, &db[16384 + ((R) + w * 8) * 64])

#define G8_SB()  asm volatile("s_barrier" ::: "memory")
#define G8_LGKM() do { asm volatile("s_waitcnt lgkmcnt(0)" ::: "memory");     \
                       __builtin_amdgcn_sched_barrier(0); } while (0)

#define G8_RDA(G) do {                                                        \
    p0 = *(const bf16x8*)&sb[abase + (2*(G)    ) * 1024 + ga0];               \
    p1 = *(const bf16x8*)&sb[abase + (2*(G)    ) * 1024 + ga1];               \
    p2 = *(const bf16x8*)&sb[abase + (2*(G) + 1) * 1024 + ga0];               \
    p3 = *(const bf16x8*)&sb[abase + (2*(G) + 1) * 1024 + ga1];               \
  } while (0)

#define G8_MFMA(G) do {                                                       \
    __builtin_amdgcn_s_setprio(1);                                            \
    _Pragma("unroll")                                                         \
    for (int n_ = 0; n_ < 3; ++n_) {                                          \
      acc[2*(G)][n_]     = mfma16(p0, bq0[n_], acc[2*(G)][n_]);               \
      acc[2*(G)][n_]     = mfma16(p1, bq1[n_], acc[2*(G)][n_]);               \
      acc[2*(G) + 1][n_] = mfma16(p2, bq0[n_], acc[2*(G) + 1][n_]);           \
      acc[2*(G) + 1][n_] = mfma16(p3, bq1[n_], acc[2*(G) + 1][n_]);           \
    }                                                                         \
    __builtin_amdgcn_sched_barrier(0);                                        \
    __builtin_amdgcn_s_setprio(0);                                            \
  } while (0)

#define G8_TILE(DOSTAGE, VM1, VM3) do {                                       \
    bf16x8 bq0[3], bq1[3], p0, p1, p2, p3;                                    \
    /* ---- phase 0 ---- */                                                   \
    _Pragma("unroll")                                                         \
    for (int n_ = 0; n_ < 3; ++n_) {                                          \
      bq0[n_] = *(const bf16x8*)&sb[bbase + n_ * 1024 + ga0];                 \
      bq1[n_] = *(const bf16x8*)&sb[bbase + n_ * 1024 + ga1];                 \
    }                                                                         \
    G8_RDA(0);                                                                \
    if (DOSTAGE) { QSTB(0); QSTB(64); }                                       \
    G8_SB(); G8_LGKM();                                                       \
    G8_MFMA(0);                                                               \
    G8_SB();                                                                  \
    /* ---- phase 1 ---- */                                                   \
    G8_RDA(1);                                                                \
    if (DOSTAGE) { QSTB(128); QSTA(0); }                                      \
    asm volatile("s_waitcnt " VM1 ::: "memory");                              \
    G8_SB(); G8_LGKM();                                                       \
    G8_MFMA(1);                                                               \
    G8_SB();                                                                  \
    /* ---- phase 2 ---- */                                                   \
    G8_RDA(2);                                                                \
    if (DOSTAGE) { QSTA(128); QSTA(64); }                                     \
    G8_SB(); G8_LGKM();                                                       \
    G8_MFMA(2);                                                               \
    G8_SB();                                                                  \
    /* ---- phase 3 ---- */                                                   \
    G8_RDA(3);                                                                \
    if (DOSTAGE) { QSTA(192); }                                               \
    asm volatile("s_waitcnt " VM3 ::: "memory");                              \
    G8_SB(); G8_LGKM();                                                       \
    G8_MFMA(3);                                                               \
    G8_SB();                                                                  \
  } while (0)

// grid: 512 blocks (16 m x 32 n), XCD-swizzled (512 % 8 == 0).
__global__ __launch_bounds__(512, 2) void qkv_gemm(
    const unsigned short* __restrict__ A,
    const unsigned short* __restrict__ B,
    const float* __restrict__ bias,
    unsigned short* __restrict__ Qo,
    unsigned short* __restrict__ Ko,
    unsigned short* __restrict__ Vo)
{
  __shared__ unsigned short smb[2 * QBUFS];   // 112 KB
  const int id  = blockIdx.x;
  const int swz = (id & 7) * 64 + (id >> 3);
  const int m0 = (swz >> 5) * 256, n0 = (swz & 31) * 192;
  const int t = threadIdx.x, l = t & 63, w = t >> 6;
  const int wm = w >> 2, wn = w & 3;
  const int fr = l & 15, fg = l >> 4;
  const int abase = (wm * 128 + fr) * 64;
  const int bbase = 16384 + (wn * 48 + fr) * 64;
  const int ga0 = ((fg     ) ^ (fr & 7)) * 8;
  const int ga1 = ((fg + 4 ) ^ (fr & 7)) * 8;
  const int srcrow = w * 8 + (l >> 3);
  const int sgr    = ((l & 7) ^ (l >> 3)) * 8;
  const unsigned short* Asrc = A + (size_t)(m0 + srcrow) * KDIM + sgr;
  const unsigned short* Bsrc = B + (size_t)(n0 + srcrow) * KDIM + sgr;
  f32x4 acc[8][3] = {};

  { // prologue: stage tile 0 (order: B0,B64,B128,A0,A128,A64,A192)
    unsigned short* db = smb;
    size_t koff = 0;
    QSTB(0); QSTB(64); QSTB(128);
    QSTA(0); QSTA(128); QSTA(64); QSTA(192);
  }
  asm volatile("s_waitcnt vmcnt(2)" ::: "memory");   // A64,A192 still in flight
  asm volatile("s_barrier" ::: "memory");

#pragma unroll 1
  for (int kt = 0; kt < NT64 - 1; ++kt) {
    const unsigned short* sb = &smb[(kt & 1) * QBUFS];
    unsigned short* db = &smb[((kt + 1) & 1) * QBUFS];
    size_t koff = (size_t)(kt + 1) * BK64;
    G8_TILE(1, "vmcnt(4)", "vmcnt(2)");
  }
  { // last tile: no staging; drain remaining A64,A192 at ph1
    const unsigned short* sb = &smb[((NT64 - 1) & 1) * QBUFS];
    unsigned short* db = smb;    // unused (DOSTAGE=0)
    size_t koff = 0; (void)koff;
    G8_TILE(0, "vmcnt(0)", "vmcnt(0)");
  }

  // epilogue: bias (+ q-scale fold) + scatter to [b][h][s][d] bf16
#pragma unroll
  for (int n = 0; n < 3; ++n) {
    int ncol = n0 + wn * 48 + n * 16 + fr;
    float bv = bias[ncol];
    int head = ncol / 384;
    int rem  = ncol - head * 384;
    int wi   = rem >> 7;          // 0=q 1=k 2=v
    int d    = rem & 127;
    unsigned short* dst = (wi == 0) ? Qo : ((wi == 1) ? Ko : Vo);
#pragma unroll
    for (int m = 0; m < 8; ++m) {
#pragma unroll
      for (int j = 0; j < 4; ++j) {
        int r = m0 + wm * 128 + m * 16 + fg * 4 + j;
        int s = r >> 1, bb = r & 1;
        float val = acc[m][n][j] + bv;
        if (wi == 0) val *= 0.08838834764831845f;   // fold 1/sqrt(128) into Q
        dst[(((size_t)(bb * NH + head)) * SEQ + s) * HD + d] = f2bf(val);
      }
    }
  }
}

// =====================================================================
// dense GEMM: BM=256, BN=128, BK=64, 3-buf rotation (round-4 structure)
// =====================================================================

#define GEMM_PRE()                                                            \
  const int t = threadIdx.x, l = t & 63, w = t >> 6;                          \
  const int wm = w >> 1, wn = w & 1;                                          \
  const int fr = l & 15, fg = l >> 4;                                         \
  const int fx = fr & 7;                                                      \
  const int srow = l >> 3;                                                    \
  const int sgr  = ((l & 7) ^ srow) * 8;                                      \
  const unsigned short* Aw = A + (size_t)(m0 + w * 32 + srow) * KDIM + sgr;   \
  const unsigned short* Bw = B + (size_t)(n0 + w * 16 + srow) * KDIM + sgr;   \
  unsigned short* smb = &sm[0][0];                                            \
  const int a0 = (wm * 64 + fr) * 64 + ((fg ^ fx) * 8);                       \
  const int a1 = (wm * 64 + fr) * 64 + (((4 + fg) ^ fx) * 8);                 \
  const int b0 = 16384 + (wn * 64 + fr) * 64 + ((fg ^ fx) * 8);               \
  const int b1 = 16384 + (wn * 64 + fr) * 64 + (((4 + fg) ^ fx) * 8);         \
  f32x4 acc[4][4] = {};

#define STAGE_AB(KT) do {                                                     \
    unsigned short* dst = &smb[((KT) % 3) * 24576];                           \
    const unsigned short* ap = Aw + (size_t)(KT) * BK64;                      \
    gl_lds16(ap,                    &dst[(w * 4 + 0) * 512]);                 \
    gl_lds16(ap + 8  * KDIM,        &dst[(w * 4 + 1) * 512]);                 \
    gl_lds16(ap + 16 * KDIM,        &dst[(w * 4 + 2) * 512]);                 \
    gl_lds16(ap + 24 * KDIM,        &dst[(w * 4 + 3) * 512]);                 \
    const unsigned short* bp = Bw + (size_t)(KT) * BK64;                      \
    gl_lds16(bp,                    &dst[16384 + (w * 2 + 0) * 512]);         \
    gl_lds16(bp + 8 * KDIM,         &dst[16384 + (w * 2 + 1) * 512]);         \
  } while (0)

#define GEMM_BODY(KT, VM, DOSTAGE) do {                                       \
    const unsigned short* sb = &smb[((KT) % 3) * 24576];                      \
    if (DOSTAGE) STAGE_AB((KT) + 2);                                          \
    bf16x8 af0[4], af1[4], bg0[4], bg1[4];                                    \
    _Pragma("unroll")                                                         \
    for (int m_ = 0; m_ < 4; ++m_) {                                          \
      af0[m_] = *(const bf16x8*)&sb[a0 + m_ * 1024];                          \
      af1[m_] = *(const bf16x8*)&sb[a1 + m_ * 1024];                          \
    }                                                                         \
    _Pragma("unroll")                                                         \
    for (int n_ = 0; n_ < 4; ++n_) {                                          \
      bg0[n_] = *(const bf16x8*)&sb[b0 + n_ * 1024];                          \
      bg1[n_] = *(const bf16x8*)&sb[b1 + n_ * 1024];                          \
    }                                                                         \
    asm volatile("s_waitcnt vmcnt(" #VM ")" ::: "memory");                    \
    asm volatile("s_barrier" ::: "memory");                                   \
    asm volatile("s_waitcnt lgkmcnt(0)" ::: "memory");                        \
    __builtin_amdgcn_sched_barrier(0);                                        \
    __builtin_amdgcn_s_setprio(1);                                            \
    _Pragma("unroll")                                                         \
    for (int m_ = 0; m_ < 4; ++m_)                                            \
      _Pragma("unroll")                                                       \
      for (int n_ = 0; n_ < 4; ++n_)                                          \
        acc[m_][n_] = mfma16(af0[m_], bg0[n_], acc[m_][n_]);                  \
    _Pragma("unroll")                                                         \
    for (int m_ = 0; m_ < 4; ++m_)                                            \
      _Pragma("unroll")                                                       \
      for (int n_ = 0; n_ < 4; ++n_)                                          \
        acc[m_][n_] = mfma16(af1[m_], bg1[n_], acc[m_][n_]);                  \
    __builtin_amdgcn_sched_barrier(0);                                        \
    __builtin_amdgcn_s_setprio(0);                                            \
    asm volatile("s_barrier" ::: "memory");                                   \
  } while (0)

#define GEMM_MAIN()                                                           \
  STAGE_AB(0); STAGE_AB(1);                                                   \
  asm volatile("s_waitcnt vmcnt(6)" ::: "memory");                            \
  asm volatile("s_barrier" ::: "memory");                                     \
  _Pragma("unroll 1")                                                         \
  for (int kt = 0; kt < NT64 - 2; ++kt)                                       \
    GEMM_BODY(kt, 6, 1);                                                      \
  GEMM_BODY(NT64 - 2, 0, 0);                                                  \
  GEMM_BODY(NT64 - 1, 0, 0);

// grid: 256 blocks (16 x 16), XCD-swizzled.
__global__ __launch_bounds__(512, 1) void dense_gemm(
    const unsigned short* __restrict__ A,
    const unsigned short* __restrict__ B,
    const float* __restrict__ bias,
    float* __restrict__ out)
{
  __shared__ unsigned short sm[3][24576];   // 144KB
  int id  = blockIdx.x;
  int swz = (id & 7) * (gridDim.x >> 3) + (id >> 3);
  const int m0 = (swz / 16) * 256, n0 = (swz % 16) * 128;
  GEMM_PRE();
  GEMM_MAIN();

  const int g4 = fg * 4;
#pragma unroll
  for (int n = 0; n < 4; ++n) {
    int ncol = n0 + wn * 64 + n * 16 + fr;
    float bv = bias[ncol];
#pragma unroll
    for (int m = 0; m < 4; ++m) {
#pragma unroll
      for (int j = 0; j < 4; ++j) {
        int r = m0 + wm * 64 + m * 16 + g4 + j;
        out[(size_t)r * HID + ncol] = acc[m][n][j] + bv;
      }
    }
  }
}

// ---------------- causal flash attention, paired q-tiles ----------------
// grid (16 pairs, 32 bh); block 256 = 4 waves x 16 q-rows per tile.
// Block handles q-tiles {pair, 31-pair}: exactly 33 tile-computes each.
__global__ __launch_bounds__(256, 2) void attn_fwd(
    const unsigned short* __restrict__ Q,
    const unsigned short* __restrict__ K,
    const unsigned short* __restrict__ Vt,   // [bh][d][s]
    unsigned short* __restrict__ ctx)
{
  __shared__ unsigned short Ksh[2][64 * 128];   // swizzled granules, 16KB each
  __shared__ unsigned short Vsh[2][128 * 64];   // [d][key] swizzled, 16KB each
  __shared__ unsigned short Psh[4][16 * 72];    // per-wave P tile
  const int t = threadIdx.x, l = t & 63, w = t >> 6;
  int nwg = gridDim.x * gridDim.y;              // 512
  int id  = blockIdx.y * gridDim.x + blockIdx.x;
  int swz = (id & 7) * (nwg >> 3) + (id >> 3);
  const int pair = swz & 15;
  const int bh   = swz >> 4;
  const int qtA = pair, qtB = 31 - pair;
  const int fr = l & 15, fg = l >> 4;
  const size_t base  = (size_t)bh * SEQ * HD;
  const size_t vbase = (size_t)bh * HD * SEQ;

#define STAGE(BUF, KT) do {                                                   \
    const unsigned short* Kt_ = K + base + (size_t)((KT) * 64) * HD;          \
    _Pragma("unroll")                                                         \
    for (int i_ = 0; i_ < 4; ++i_) {                                          \
      int ch_  = w * 4 + i_;                                                  \
      int row_ = ch_ * 4 + (l >> 4);                                          \
      int c16_ = (l & 15) ^ (row_ & 7);                                       \
      gl_lds16(Kt_ + (size_t)row_ * HD + c16_ * 8, &Ksh[BUF][ch_ * 512]);     \
    }                                                                         \
    const unsigned short* Vg_ = Vt + vbase + (KT) * 64;                       \
    _Pragma("unroll")                                                         \
    for (int i_ = 0; i_ < 4; ++i_) {                                          \
      int ch_  = w * 4 + i_;                                                  \
      int row_ = ch_ * 8 + (l >> 3);                                          \
      int c16_ = (l & 7) ^ (row_ & 7);                                        \
      gl_lds16(Vg_ + (size_t)row_ * SEQ + c16_ * 8, &Vsh[BUF][ch_ * 512]);    \
    }                                                                         \
  } while (0)

#define COMPUTE_TILE(QF, OACC, MROW, LROW, QT) do {                           \
    f32x4 sacc[4] = {};                                                       \
    _Pragma("unroll")                                                         \
    for (int c_ = 0; c_ < 4; ++c_) {                                          \
      _Pragma("unroll")                                                       \
      for (int n_ = 0; n_ < 4; ++n_) {                                        \
        int krow = n_ * 16 + fr;                                              \
        int g_   = (c_ * 4 + fg) ^ (krow & 7);                                \
        bf16x8 kf = *(const bf16x8*)&Ksh[buf][krow * 128 + g_ * 8];           \
        sacc[n_] = mfma16(QF[c_], kf, sacc[n_]);                              \
      }                                                                       \
    }                                                                         \
    if (kt == (QT)) {                                                         \
      _Pragma("unroll")                                                       \
      for (int n_ = 0; n_ < 4; ++n_)                                          \
        _Pragma("unroll")                                                     \
        for (int j_ = 0; j_ < 4; ++j_)                                        \
          if (n_ * 16 + fr > w * 16 + fg * 4 + j_) sacc[n_][j_] = -1e30f;     \
    }                                                                         \
    float tm_[4];                                                             \
    _Pragma("unroll")                                                         \
    for (int j_ = 0; j_ < 4; ++j_) {                                          \
      float v0 = fmaxf(fmaxf(sacc[0][j_], sacc[1][j_]),                       \
                       fmaxf(sacc[2][j_], sacc[3][j_]));                      \
      v0 = fmaxf(v0, __shfl_xor(v0, 1));                                      \
      v0 = fmaxf(v0, __shfl_xor(v0, 2));                                      \
      v0 = fmaxf(v0, __shfl_xor(v0, 4));                                      \
      v0 = fmaxf(v0, __shfl_xor(v0, 8));                                      \
      tm_[j_] = v0;                                                           \
    }                                                                         \
    float sc_[4], ps_[4];                                                     \
    _Pragma("unroll")                                                         \
    for (int j_ = 0; j_ < 4; ++j_) {                                          \
      float mn_ = fmaxf(MROW[j_], tm_[j_]);                                   \
      sc_[j_] = exp2f((MROW[j_] - mn_) * LOG2E);                              \
      MROW[j_] = mn_;                                                         \
      ps_[j_] = 0.f;                                                          \
    }                                                                         \
    _Pragma("unroll")                                                         \
    for (int n_ = 0; n_ < 4; ++n_)                                            \
      _Pragma("unroll")                                                       \
      for (int j_ = 0; j_ < 4; ++j_) {                                        \
        float p_ = exp2f((sacc[n_][j_] - MROW[j_]) * LOG2E);                  \
        sacc[n_][j_] = p_;                                                    \
        ps_[j_] += p_;                                                        \
      }                                                                       \
    _Pragma("unroll")                                                         \
    for (int j_ = 0; j_ < 4; ++j_) {                                          \
      float s_ = ps_[j_];                                                     \
      s_ += __shfl_xor(s_, 1);                                                \
      s_ += __shfl_xor(s_, 2);                                                \
      s_ += __shfl_xor(s_, 4);                                                \
      s_ += __shfl_xor(s_, 8);                                                \
      LROW[j_] = LROW[j_] * sc_[j_] + s_;                                     \
    }                                                                         \
    _Pragma("unroll")                                                         \
    for (int n_ = 0; n_ < 8; ++n_)                                            \
      _Pragma("unroll")                                                       \
      for (int j_ = 0; j_ < 4; ++j_)                                          \
        OACC[n_][j_] *= sc_[j_];                                              \
    _Pragma("unroll")                                                         \
    for (int n_ = 0; n_ < 4; ++n_)                                            \
      _Pragma("unroll")                                                       \
      for (int j_ = 0; j_ < 4; ++j_)                                          \
        Psh[w][(fg * 4 + j_) * 72 + n_ * 16 + fr] = f2bf(sacc[n_][j_]);       \
    _Pragma("unroll")                                                         \
    for (int ks_ = 0; ks_ < 2; ++ks_) {                                       \
      bf16x8 pf = *(const bf16x8*)&Psh[w][fr * 72 + ks_ * 32 + fg * 8];       \
      _Pragma("unroll")                                                       \
      for (int n_ = 0; n_ < 8; ++n_) {                                        \
        int vrow = n_ * 16 + fr;                                              \
        int g_   = (ks_ * 4 + fg) ^ (vrow & 7);                               \
        bf16x8 vf = *(const bf16x8*)&Vsh[buf][vrow * 64 + g_ * 8];            \
        OACC[n_] = mfma16(pf, vf, OACC[n_]);                                  \
      }                                                                       \
    }                                                                         \
  } while (0)

  // Q fragments for both tiles (scale folded in at QKV epilogue)
  bf16x8 qfA[4], qfB[4];
  {
    const unsigned short* qpA = Q + base + (size_t)(qtA * 64 + w * 16 + fr) * HD + fg * 8;
    const unsigned short* qpB = Q + base + (size_t)(qtB * 64 + w * 16 + fr) * HD + fg * 8;
#pragma unroll
    for (int c = 0; c < 4; ++c) {
      qfA[c] = *(const bf16x8*)(qpA + c * 32);
      qfB[c] = *(const bf16x8*)(qpB + c * 32);
    }
  }
  f32x4 oaccA[8] = {}, oaccB[8] = {};
  float mA[4] = {-1e30f, -1e30f, -1e30f, -1e30f};
  float mB[4] = {-1e30f, -1e30f, -1e30f, -1e30f};
  float lA[4] = {0.f, 0.f, 0.f, 0.f};
  float lB[4] = {0.f, 0.f, 0.f, 0.f};

  STAGE(0, 0);
  __syncthreads();
  int buf = 0;
  for (int kt = 0; kt <= qtB; ++kt) {
    if (kt < qtB) STAGE(buf ^ 1, kt + 1);       // prefetch hides under compute
    COMPUTE_TILE(qfB, oaccB, mB, lB, qtB);
    if (kt <= qtA) COMPUTE_TILE(qfA, oaccA, mA, lA, qtA);
    __syncthreads();                            // drains vmcnt -> next buf ready
    buf ^= 1;
  }

  const int bb = bh >> 4, h = bh & 15;
#define WRITE_CTX(OACC, LROW, QT) do {                                        \
    _Pragma("unroll")                                                         \
    for (int n_ = 0; n_ < 8; ++n_)                                            \
      _Pragma("unroll")                                                       \
      for (int j_ = 0; j_ < 4; ++j_) {                                        \
        int qrow = (QT) * 64 + w * 16 + fg * 4 + j_;                          \
        float val = OACC[n_][j_] / LROW[j_];                                  \
        ctx[((size_t)(qrow * BATCH + bb)) * HID + h * HD + n_ * 16 + fr] =    \
            f2bf(val);                                                        \
      }                                                                       \
  } while (0)
  WRITE_CTX(oaccA, lA, qtA);
  WRITE_CTX(oaccB, lB, qtB);
#undef STAGE
#undef COMPUTE_TILE
#undef WRITE_CTX
}

// ---------------- launcher ----------------
extern "C" void kernel_launch(void* const* d_in, const int* in_sizes, int n_in,
                              void* d_out, int out_size, void* d_ws, size_t ws_size,
                              hipStream_t stream) {
  const float* hs      = (const float*)d_in[0];
  const float* w_qkv   = (const float*)d_in[1];
  const float* b_qkv   = (const float*)d_in[2];
  const float* w_dense = (const float*)d_in[3];
  const float* b_dense = (const float*)d_in[4];
  float* out = (float*)d_out;

  unsigned short* hsb = (unsigned short*)d_ws;              // 8.4M shorts
  unsigned short* wqb = hsb + (size_t)MTOT * HID;
  unsigned short* wdb = wqb + (size_t)NQKV * HID;
  unsigned short* q   = wdb + (size_t)HID * HID;
  unsigned short* k   = q   + (size_t)MTOT * HID;
  unsigned short* v   = k   + (size_t)MTOT * HID;
  unsigned short* ctx = v   + (size_t)MTOT * HID;
  unsigned short* vt  = hsb;   // alias: hsb dead after qkv_gemm, vt written before attn

  cvt3_f32_bf16<<<2048, 256, 0, stream>>>(
      hs, hsb, (MTOT * HID) / 4,
      w_qkv, wqb, (NQKV * HID) / 4,
      w_dense, wdb, (HID * HID) / 4);

  qkv_gemm<<<dim3((MTOT / 256) * (NQKV / 192)), 512, 0, stream>>>(hsb, wqb, b_qkv, q, k, v);
  transpose_v<<<dim3(SEQ / 64, HD / 64, BATCH * NH), 256, 0, stream>>>(v, vt);
  attn_fwd<<<dim3(16, 32), 256, 0, stream>>>(q, k, vt, ctx);
  dense_gemm<<<dim3((MTOT / 256) * (HID / 128)), 512, 0, stream>>>(ctx, wdb, b_dense, out);
}